// Round 7
// baseline (346.966 us; speedup 1.0000x reference)
//
#include <hip/hip_runtime.h>

typedef __attribute__((ext_vector_type(8))) short bf16x8;
typedef __attribute__((ext_vector_type(4))) float f32x4;
typedef __attribute__((ext_vector_type(2))) float f32x2;

__device__ __forceinline__ unsigned short f2bf(float x) {
  union { float f; unsigned u; } v; v.f = x;
  return (unsigned short)((v.u + 0x7fffu + ((v.u >> 16) & 1u)) >> 16);
}
__device__ __forceinline__ float bf2f(unsigned short h) {
  union { unsigned u; float f; } v; v.u = ((unsigned)h) << 16; return v.f;
}

// ================= CSR build: two-level counting sort by dst =================
// Bucket = dst >> 8 (256 nodes/bucket). Record = (dst&255)<<17 | src (25 bits).
// bcnt/bfill: one counter per 64B line (stride-16 ints) to avoid L2 atomic slamming.

__global__ __launch_bounds__(256) void bhist_k(const int* __restrict__ dst,
                                               int* __restrict__ bcnt, int E, int B) {
  __shared__ int h[512];
  for (int i = threadIdx.x; i < B; i += 256) h[i] = 0;
  __syncthreads();
  for (int e = blockIdx.x * 256 + threadIdx.x; e < E; e += gridDim.x * 256)
    atomicAdd(&h[dst[e] >> 8], 1);
  __syncthreads();
  for (int i = threadIdx.x; i < B; i += 256)
    if (h[i]) atomicAdd(&bcnt[i * 16], h[i]);
}

// -- binning: local bucket scan + per-block LDS hist + one reservation per (block,bucket) --
__global__ __launch_bounds__(256) void bin_k(const int* __restrict__ src,
                                             const int* __restrict__ dst,
                                             const int* __restrict__ bcnt,
                                             int* __restrict__ bfill,
                                             unsigned* __restrict__ ebuf, int E, int B) {
  __shared__ int hist[512];
  __shared__ int base[512];
  __shared__ int sd[256];
  int t = threadIdx.x;
  // local exclusive scan of bucket counts (2 elems/thread over 512 slots)
  int i0 = 2 * t, i1 = 2 * t + 1;
  int v0 = (i0 < B) ? bcnt[i0 * 16] : 0;
  int v1 = (i1 < B) ? bcnt[i1 * 16] : 0;
  int ts = v0 + v1;
  sd[t] = ts; __syncthreads();
  for (int off = 1; off < 256; off <<= 1) {
    int x = (t >= off) ? sd[t - off] : 0;
    __syncthreads();
    sd[t] += x;
    __syncthreads();
  }
  int excl = sd[t] - ts;
  base[i0] = excl;
  base[i1] = excl + v0;
  __syncthreads();  // base[] = global bucket starts

  int chunk = (E + gridDim.x - 1) / gridDim.x;
  int e0 = blockIdx.x * chunk;
  int e1 = e0 + chunk; if (e1 > E) e1 = E;
  for (int i = t; i < B; i += 256) hist[i] = 0;
  __syncthreads();
  for (int e = e0 + t; e < e1; e += 256) atomicAdd(&hist[dst[e] >> 8], 1);
  __syncthreads();
  for (int i = t; i < B; i += 256) {
    int c = hist[i];
    hist[i] = base[i] + (c ? atomicAdd(&bfill[i * 16], c) : 0);  // running cursor
  }
  __syncthreads();
  for (int e = e0 + t; e < e1; e += 256) {
    int d = dst[e];
    int b = d >> 8;
    int pos = atomicAdd(&hist[b], 1);  // LDS atomic
    ebuf[pos] = ((unsigned)(d & 255) << 17) | (unsigned)src[e];
  }
}

// -- per-bucket LDS counting sort -> coalesced CSR + row_start + dinv --
__global__ __launch_bounds__(256) void bsort_k(const unsigned* __restrict__ ebuf,
                                               const int* __restrict__ bcnt,
                                               int* __restrict__ csr,
                                               int* __restrict__ row_start,
                                               float* __restrict__ dinv, int N, int B, int E) {
  __shared__ int cnt[256];
  __shared__ int sd[256];
  __shared__ int ofs[256];
  __shared__ int sorted[8192];  // mean 4096, sigma ~64 -> cap is +64 sigma
  __shared__ int s_bs, s_m;
  int b = blockIdx.x, t = threadIdx.x;
  // local exclusive scan to find this bucket's start + size
  int i0 = 2 * t, i1 = 2 * t + 1;
  int v0 = (i0 < B) ? bcnt[i0 * 16] : 0;
  int v1 = (i1 < B) ? bcnt[i1 * 16] : 0;
  int ts = v0 + v1;
  sd[t] = ts; __syncthreads();
  for (int off = 1; off < 256; off <<= 1) {
    int x = (t >= off) ? sd[t - off] : 0;
    __syncthreads();
    sd[t] += x;
    __syncthreads();
  }
  int excl = sd[t] - ts;
  if (i0 == b) { s_bs = excl; s_m = v0; }
  if (i1 == b) { s_bs = excl + v0; s_m = v1; }
  if (b == 0 && t == 0) row_start[N] = E;
  __syncthreads();
  int bs = s_bs, m = s_m;
  if (m > 8192) m = 8192;  // unreachable safety clamp

  cnt[t] = 0;
  __syncthreads();
  for (int i = t; i < m; i += 256) atomicAdd(&cnt[ebuf[bs + i] >> 17], 1);
  __syncthreads();
  int deg = cnt[t];
  sd[t] = deg; __syncthreads();
  for (int off = 1; off < 256; off <<= 1) {
    int x = (t >= off) ? sd[t - off] : 0;
    __syncthreads();
    sd[t] += x;
    __syncthreads();
  }
  int nexcl = sd[t] - deg;
  ofs[t] = nexcl;
  int node = (b << 8) + t;
  if (node < N) {
    row_start[node] = bs + nexcl;
    dinv[node] = rsqrtf((float)(deg + 1));
  }
  __syncthreads();
  for (int i = t; i < m; i += 256) {
    unsigned r = ebuf[bs + i];
    int d = r >> 17;
    int p = atomicAdd(&ofs[d], 1);
    if (p < 8192) sorted[p] = (int)(r & 0x1FFFFu);
  }
  __syncthreads();
  for (int i = t; i < m; i += 256) csr[bs + i] = sorted[i];
}

// -- edge weight precompute: csrw[e] = {src, dinv[src]} --
__global__ __launch_bounds__(256) void wfill_k(const int* __restrict__ csr,
                                               const float* __restrict__ dinv,
                                               int2* __restrict__ csrw, int E) {
  int e = blockIdx.x * 256 + threadIdx.x;
  if (e < E) {
    int s = csr[e];
    csrw[e] = make_int2(s, __float_as_int(dinv[s]));
  }
}

// ---------------- GEMM: [M,128] @ [128,NCOL] via 16x16x32 bf16 MFMA ----------------
template <int NCOL, bool INF32, bool OUTF32>
__global__ __launch_bounds__(256) void gemm_k(const void* __restrict__ Ap,
                                              const float* __restrict__ W,
                                              const float* __restrict__ bias,
                                              void* __restrict__ Cp, int M) {
  __shared__ __align__(16) unsigned short Ws[NCOL * 136];  // [n][k], pad k to 136
  int tid = threadIdx.x;
  for (int e = tid; e < 128 * NCOL; e += 256) {
    int k = e / NCOL, n = e % NCOL;
    Ws[n * 136 + k] = f2bf(W[e]);
  }
  __syncthreads();

  int wave = tid >> 6, lane = tid & 63;
  int q = lane >> 4, r = lane & 15;
  const int NT = NCOL / 16;
  int ntile = M >> 4;
  for (int tile = blockIdx.x * 4 + wave; tile < ntile; tile += gridDim.x * 4) {
    int row = tile * 16 + r;
    bf16x8 a[4];
    if (INF32) {
      const float* A = (const float*)Ap + (size_t)row * 128 + q * 8;
#pragma unroll
      for (int kk = 0; kk < 4; kk++) {
        const float4* p = (const float4*)(A + kk * 32);
        float4 f0 = p[0], f1 = p[1];
        bf16x8 tt;
        tt[0] = (short)f2bf(f0.x); tt[1] = (short)f2bf(f0.y);
        tt[2] = (short)f2bf(f0.z); tt[3] = (short)f2bf(f0.w);
        tt[4] = (short)f2bf(f1.x); tt[5] = (short)f2bf(f1.y);
        tt[6] = (short)f2bf(f1.z); tt[7] = (short)f2bf(f1.w);
        a[kk] = tt;
      }
    } else {
      const unsigned short* A = (const unsigned short*)Ap + (size_t)row * 128 + q * 8;
#pragma unroll
      for (int kk = 0; kk < 4; kk++) a[kk] = *(const bf16x8*)(A + kk * 32);
    }
    f32x4 acc[NT];
#pragma unroll
    for (int nt = 0; nt < NT; nt++) { acc[nt][0] = 0.f; acc[nt][1] = 0.f; acc[nt][2] = 0.f; acc[nt][3] = 0.f; }
#pragma unroll
    for (int kk = 0; kk < 4; kk++) {
#pragma unroll
      for (int nt = 0; nt < NT; nt++) {
        bf16x8 bfr = *(const bf16x8*)&Ws[(nt * 16 + r) * 136 + kk * 32 + q * 8];
        acc[nt] = __builtin_amdgcn_mfma_f32_16x16x32_bf16(a[kk], bfr, acc[nt], 0, 0, 0);
      }
    }
#pragma unroll
    for (int nt = 0; nt < NT; nt++) {
#pragma unroll
      for (int rr = 0; rr < 4; rr++) {
        int orow = tile * 16 + q * 4 + rr;
        int ocol = nt * 16 + r;
        if (OUTF32)
          ((float*)Cp)[(size_t)orow * NCOL + ocol] = acc[nt][rr] + bias[ocol];
        else
          ((unsigned short*)Cp)[(size_t)orow * NCOL + ocol] = f2bf(acc[nt][rr]);
      }
    }
  }
}

// ---------------- aggregation v4: wave/node, 16 edges in flight, packed f32x2 FMA ----
// lane = (g = lane>>4, r = lane&15). Accumulators are 4x float2 (features 2d, 2d+1);
// bf16->f32 via bit ops so the pair feeds one v_pk_fma_f32.
__global__ __launch_bounds__(256) void agg_k(const unsigned short* __restrict__ h,
                                             const float* __restrict__ dinv,
                                             const int* __restrict__ row_start,
                                             const int2* __restrict__ csrw,
                                             const float* __restrict__ bias,
                                             unsigned short* __restrict__ out, int N) {
  int lane = threadIdx.x & 63;
  int node = (blockIdx.x * 256 + threadIdx.x) >> 6;
  if (node >= N) return;
  int g = lane >> 4, r = lane & 15;
  float di = dinv[node];
  int beg = row_start[node];
  int deg = row_start[node + 1] - beg;

  f32x2 acc2[4];
#pragma unroll
  for (int i = 0; i < 4; i++) { acc2[i][0] = 0.f; acc2[i][1] = 0.f; }

#define ACC8(U, WV)                                                            \
  {                                                                            \
    f32x2 w2; w2[0] = (WV); w2[1] = (WV);                                      \
    f32x2 p0, p1, p2, p3;                                                      \
    p0[0] = __uint_as_float((U).x << 16);                                      \
    p0[1] = __uint_as_float((U).x & 0xffff0000u);                              \
    p1[0] = __uint_as_float((U).y << 16);                                      \
    p1[1] = __uint_as_float((U).y & 0xffff0000u);                              \
    p2[0] = __uint_as_float((U).z << 16);                                      \
    p2[1] = __uint_as_float((U).z & 0xffff0000u);                              \
    p3[0] = __uint_as_float((U).w << 16);                                      \
    p3[1] = __uint_as_float((U).w & 0xffff0000u);                              \
    acc2[0] += p0 * w2; acc2[1] += p1 * w2;                                    \
    acc2[2] += p2 * w2; acc2[3] += p3 * w2;                                    \
  }

  for (int base = -1; base < deg; base += 64) {
    int idx = base + lane;
    int s = node; float wv = 0.f;
    if (idx < 0) { wv = di; }  // virtual self edge
    else if (idx < deg) {
      int2 rec = csrw[beg + idx];
      s = rec.x; wv = __int_as_float(rec.y);
    }
    int cntv = deg - base; if (cntv > 64) cntv = 64;
    int j = 0;
    for (; j + 16 <= cntv; j += 16) {
      int s0 = __shfl(s, j + g);       float w0 = __shfl(wv, j + g);
      int s1 = __shfl(s, j + 4 + g);   float w1 = __shfl(wv, j + 4 + g);
      int s2 = __shfl(s, j + 8 + g);   float w2_ = __shfl(wv, j + 8 + g);
      int s3 = __shfl(s, j + 12 + g);  float w3 = __shfl(wv, j + 12 + g);
      uint4 u0 = *(const uint4*)(h + (size_t)s0 * 128 + r * 8);
      uint4 u1 = *(const uint4*)(h + (size_t)s1 * 128 + r * 8);
      uint4 u2 = *(const uint4*)(h + (size_t)s2 * 128 + r * 8);
      uint4 u3 = *(const uint4*)(h + (size_t)s3 * 128 + r * 8);
      ACC8(u0, w0); ACC8(u1, w1); ACC8(u2, w2_); ACC8(u3, w3);
    }
    for (; j < cntv; j += 4) {
      int sj = __shfl(s, j + g);       // slots past cntv have wv=0 (harmless)
      float wj = __shfl(wv, j + g);
      uint4 u = *(const uint4*)(h + (size_t)sj * 128 + r * 8);
      ACC8(u, wj);
    }
  }
#undef ACC8

  float a[8];
#pragma unroll
  for (int d = 0; d < 4; d++) { a[2 * d] = acc2[d][0]; a[2 * d + 1] = acc2[d][1]; }
#pragma unroll
  for (int i = 0; i < 8; i++) {
    a[i] += __shfl_xor(a[i], 16);
    a[i] += __shfl_xor(a[i], 32);
  }

  if (g == 0) {
    bf16x8 t;
#pragma unroll
    for (int i = 0; i < 8; i++) {
      float v = a[i] * di + bias[r * 8 + i];
      if (v < 0.f) v = 0.f;
      t[i] = (short)f2bf(v);
    }
    *(bf16x8*)(out + (size_t)node * 128 + r * 8) = t;
  }
}

extern "C" void kernel_launch(void* const* d_in, const int* in_sizes, int n_in,
                              void* d_out, int out_size, void* d_ws, size_t ws_size,
                              hipStream_t stream) {
  const float* x  = (const float*)d_in[0];
  const int* ei   = (const int*)d_in[1];
  const float* W1 = (const float*)d_in[2];
  const float* b1 = (const float*)d_in[3];
  const float* W2 = (const float*)d_in[4];
  const float* b2 = (const float*)d_in[5];
  const float* fcW = (const float*)d_in[6];
  const float* fcb = (const float*)d_in[7];
  float* out = (float*)d_out;

  int N = in_sizes[0] / 128;  // 100000
  int E = in_sizes[1] / 2;    // 1600000
  int B = (N + 255) >> 8;     // 391 buckets
  const int* src = ei;
  const int* dst = ei + E;

  char* w = (char*)d_ws;
  auto alloc = [&](size_t b) { char* p = w; w += (b + 255) & ~(size_t)255; return p; };
  float* dinv      = (float*)alloc((size_t)N * 4);
  int*   row_start = (int*)alloc((size_t)(N + 1) * 4);
  int*   batom     = (int*)alloc((size_t)(B + 1) * 128);  // bcnt + bfill, stride-16 each
  int*   bcnt      = batom;
  int*   bfill     = batom + (size_t)(B + 1) * 16;
  unsigned* ebuf   = (unsigned*)alloc((size_t)E * 4);
  int*   csr       = (int*)alloc((size_t)E * 4);
  int2*  csrw      = (int2*)alloc((size_t)E * 8);
  unsigned short* bufA = (unsigned short*)alloc((size_t)N * 128 * 2);
  unsigned short* bufB = (unsigned short*)alloc((size_t)N * 128 * 2);

  hipMemsetAsync(batom, 0, (size_t)(B + 1) * 128, stream);

  bhist_k<<<256, 256, 0, stream>>>(dst, bcnt, E, B);
  bin_k<<<256, 256, 0, stream>>>(src, dst, bcnt, bfill, ebuf, E, B);
  bsort_k<<<B, 256, 0, stream>>>(ebuf, bcnt, csr, row_start, dinv, N, B, E);
  wfill_k<<<(E + 255) / 256, 256, 0, stream>>>(csr, dinv, csrw, E);

  // layer 1: h1 = x @ W1   (fp32 in, bf16 out)
  gemm_k<128, true, false><<<512, 256, 0, stream>>>((const void*)x, W1, nullptr, (void*)bufA, N);
  // agg1: a1 = relu(norm-agg(h1) + b1)  (bf16)
  agg_k<<<(N + 3) / 4, 256, 0, stream>>>(bufA, dinv, row_start, csrw, b1, bufB, N);
  // layer 2: h2 = a1 @ W2
  gemm_k<128, false, false><<<512, 256, 0, stream>>>((const void*)bufB, W2, nullptr, (void*)bufA, N);
  // agg2: a2 = relu(norm-agg(h2) + b2)
  agg_k<<<(N + 3) / 4, 256, 0, stream>>>(bufA, dinv, row_start, csrw, b2, bufB, N);
  // fc: out = a2 @ fcW + fcb  (fp32 out)
  gemm_k<64, false, true><<<512, 256, 0, stream>>>((const void*)bufB, fcW, fcb, (void*)out, N);
}

// Round 8
// 334.694 us; speedup vs baseline: 1.0367x; 1.0367x over previous
//
#include <hip/hip_runtime.h>

typedef __attribute__((ext_vector_type(8))) short bf16x8;
typedef __attribute__((ext_vector_type(4))) float f32x4;
typedef __attribute__((ext_vector_type(2))) float f32x2;

__device__ __forceinline__ unsigned short f2bf(float x) {
  union { float f; unsigned u; } v; v.f = x;
  return (unsigned short)((v.u + 0x7fffu + ((v.u >> 16) & 1u)) >> 16);
}

// ================= CSR build: two-level counting sort by dst =================
// Bucket = dst >> 8 (256 nodes/bucket). Record = (dst&255)<<17 | src (25 bits).
// bcnt/bfill: one counter per 64B line (stride-16 ints).

__global__ __launch_bounds__(256) void bhist_k(const int* __restrict__ dst,
                                               int* __restrict__ bcnt, int E, int B) {
  __shared__ int h[512];
  for (int i = threadIdx.x; i < B; i += 256) h[i] = 0;
  __syncthreads();
  for (int e = blockIdx.x * 256 + threadIdx.x; e < E; e += gridDim.x * 256)
    atomicAdd(&h[dst[e] >> 8], 1);
  __syncthreads();
  for (int i = threadIdx.x; i < B; i += 256)
    if (h[i]) atomicAdd(&bcnt[i * 16], h[i]);
}

// -- binning: local bucket scan + per-block LDS hist + one reservation per (block,bucket) --
__global__ __launch_bounds__(256) void bin_k(const int* __restrict__ src,
                                             const int* __restrict__ dst,
                                             const int* __restrict__ bcnt,
                                             int* __restrict__ bfill,
                                             unsigned* __restrict__ ebuf, int E, int B) {
  __shared__ int hist[512];
  __shared__ int base[512];
  __shared__ int sd[256];
  int t = threadIdx.x;
  int i0 = 2 * t, i1 = 2 * t + 1;
  int v0 = (i0 < B) ? bcnt[i0 * 16] : 0;
  int v1 = (i1 < B) ? bcnt[i1 * 16] : 0;
  int ts = v0 + v1;
  sd[t] = ts; __syncthreads();
  for (int off = 1; off < 256; off <<= 1) {
    int x = (t >= off) ? sd[t - off] : 0;
    __syncthreads();
    sd[t] += x;
    __syncthreads();
  }
  int excl = sd[t] - ts;
  base[i0] = excl;
  base[i1] = excl + v0;
  __syncthreads();

  int chunk = (E + gridDim.x - 1) / gridDim.x;
  int e0 = blockIdx.x * chunk;
  int e1 = e0 + chunk; if (e1 > E) e1 = E;
  for (int i = t; i < B; i += 256) hist[i] = 0;
  __syncthreads();
  for (int e = e0 + t; e < e1; e += 256) atomicAdd(&hist[dst[e] >> 8], 1);
  __syncthreads();
  for (int i = t; i < B; i += 256) {
    int c = hist[i];
    hist[i] = base[i] + (c ? atomicAdd(&bfill[i * 16], c) : 0);
  }
  __syncthreads();
  for (int e = e0 + t; e < e1; e += 256) {
    int d = dst[e];
    int b = d >> 8;
    int pos = atomicAdd(&hist[b], 1);  // LDS atomic
    ebuf[pos] = ((unsigned)(d & 255) << 17) | (unsigned)src[e];
  }
}

// -- per-bucket LDS counting sort -> coalesced CSR (src only) + row_start + dinv --
__global__ __launch_bounds__(256) void bsort_k(const unsigned* __restrict__ ebuf,
                                               const int* __restrict__ bcnt,
                                               int* __restrict__ csr,
                                               int* __restrict__ row_start,
                                               float* __restrict__ dinv, int N, int B, int E) {
  __shared__ int cnt[256];
  __shared__ int sd[256];
  __shared__ int ofs[256];
  __shared__ int sorted[8192];  // mean 4096, sigma ~64
  __shared__ int s_bs, s_m;
  int b = blockIdx.x, t = threadIdx.x;
  int i0 = 2 * t, i1 = 2 * t + 1;
  int v0 = (i0 < B) ? bcnt[i0 * 16] : 0;
  int v1 = (i1 < B) ? bcnt[i1 * 16] : 0;
  int ts = v0 + v1;
  sd[t] = ts; __syncthreads();
  for (int off = 1; off < 256; off <<= 1) {
    int x = (t >= off) ? sd[t - off] : 0;
    __syncthreads();
    sd[t] += x;
    __syncthreads();
  }
  int excl = sd[t] - ts;
  if (i0 == b) { s_bs = excl; s_m = v0; }
  if (i1 == b) { s_bs = excl + v0; s_m = v1; }
  if (b == 0 && t == 0) row_start[N] = E;
  __syncthreads();
  int bs = s_bs, m = s_m;
  if (m > 8192) m = 8192;

  cnt[t] = 0;
  __syncthreads();
  for (int i = t; i < m; i += 256) atomicAdd(&cnt[ebuf[bs + i] >> 17], 1);
  __syncthreads();
  int deg = cnt[t];
  sd[t] = deg; __syncthreads();
  for (int off = 1; off < 256; off <<= 1) {
    int x = (t >= off) ? sd[t - off] : 0;
    __syncthreads();
    sd[t] += x;
    __syncthreads();
  }
  int nexcl = sd[t] - deg;
  ofs[t] = nexcl;
  int node = (b << 8) + t;
  if (node < N) {
    row_start[node] = bs + nexcl;
    dinv[node] = rsqrtf((float)(deg + 1));
  }
  __syncthreads();
  for (int i = t; i < m; i += 256) {
    unsigned r = ebuf[bs + i];
    int d = r >> 17;
    int p = atomicAdd(&ofs[d], 1);
    if (p < 8192) sorted[p] = (int)(r & 0x1FFFFu);
  }
  __syncthreads();
  for (int i = t; i < m; i += 256) csr[bs + i] = sorted[i];
}

// ---------------- GEMM: [M,128] @ [128,NCOL] via 16x16x32 bf16 MFMA ----------------
// SCALE: multiply each output row by rowscale[row] before bf16 pack (dinv folding).
template <int NCOL, bool INF32, bool OUTF32, bool SCALE>
__global__ __launch_bounds__(256) void gemm_k(const void* __restrict__ Ap,
                                              const float* __restrict__ W,
                                              const float* __restrict__ bias,
                                              const float* __restrict__ rowscale,
                                              void* __restrict__ Cp, int M) {
  __shared__ __align__(16) unsigned short Ws[NCOL * 136];  // [n][k], pad k to 136
  int tid = threadIdx.x;
  for (int e = tid; e < 128 * NCOL; e += 256) {
    int k = e / NCOL, n = e % NCOL;
    Ws[n * 136 + k] = f2bf(W[e]);
  }
  __syncthreads();

  int wave = tid >> 6, lane = tid & 63;
  int q = lane >> 4, r = lane & 15;
  const int NT = NCOL / 16;
  int ntile = M >> 4;
  for (int tile = blockIdx.x * 4 + wave; tile < ntile; tile += gridDim.x * 4) {
    int row = tile * 16 + r;
    bf16x8 a[4];
    if (INF32) {
      const float* A = (const float*)Ap + (size_t)row * 128 + q * 8;
#pragma unroll
      for (int kk = 0; kk < 4; kk++) {
        const float4* p = (const float4*)(A + kk * 32);
        float4 f0 = p[0], f1 = p[1];
        bf16x8 tt;
        tt[0] = (short)f2bf(f0.x); tt[1] = (short)f2bf(f0.y);
        tt[2] = (short)f2bf(f0.z); tt[3] = (short)f2bf(f0.w);
        tt[4] = (short)f2bf(f1.x); tt[5] = (short)f2bf(f1.y);
        tt[6] = (short)f2bf(f1.z); tt[7] = (short)f2bf(f1.w);
        a[kk] = tt;
      }
    } else {
      const unsigned short* A = (const unsigned short*)Ap + (size_t)row * 128 + q * 8;
#pragma unroll
      for (int kk = 0; kk < 4; kk++) a[kk] = *(const bf16x8*)(A + kk * 32);
    }
    f32x4 acc[NT];
#pragma unroll
    for (int nt = 0; nt < NT; nt++) { acc[nt][0] = 0.f; acc[nt][1] = 0.f; acc[nt][2] = 0.f; acc[nt][3] = 0.f; }
#pragma unroll
    for (int kk = 0; kk < 4; kk++) {
#pragma unroll
      for (int nt = 0; nt < NT; nt++) {
        bf16x8 bfr = *(const bf16x8*)&Ws[(nt * 16 + r) * 136 + kk * 32 + q * 8];
        acc[nt] = __builtin_amdgcn_mfma_f32_16x16x32_bf16(a[kk], bfr, acc[nt], 0, 0, 0);
      }
    }
#pragma unroll
    for (int rr = 0; rr < 4; rr++) {
      int orow = tile * 16 + q * 4 + rr;
      float rs = SCALE ? rowscale[orow] : 1.f;
#pragma unroll
      for (int nt = 0; nt < NT; nt++) {
        int ocol = nt * 16 + r;
        if (OUTF32)
          ((float*)Cp)[(size_t)orow * NCOL + ocol] = acc[nt][rr] + bias[ocol];
        else
          ((unsigned short*)Cp)[(size_t)orow * NCOL + ocol] = f2bf(acc[nt][rr] * rs);
      }
    }
  }
}

// ---------------- aggregation v5: pre-scaled rows -> pure sum, weightless ----------
// hs rows are already h*dinv[src]. out = relu((Σ_{s∈in∪self} hs[s]) * dinv[node] + b).
// lane = (g = lane>>4, r = lane&15); 8 edges in flight; main loop is mask-free.
__global__ __launch_bounds__(256) void agg_k(const unsigned short* __restrict__ hs,
                                             const float* __restrict__ dinv,
                                             const int* __restrict__ row_start,
                                             const int* __restrict__ csr,
                                             const float* __restrict__ bias,
                                             unsigned short* __restrict__ out, int N) {
  int lane = threadIdx.x & 63;
  int node = (blockIdx.x * 256 + threadIdx.x) >> 6;
  if (node >= N) return;
  int g = lane >> 4, r = lane & 15;
  float di = dinv[node];
  int beg = row_start[node];
  int deg = row_start[node + 1] - beg;

  f32x2 acc2[4];
#pragma unroll
  for (int i = 0; i < 4; i++) { acc2[i][0] = 0.f; acc2[i][1] = 0.f; }

#define ACCADD(U)                                                              \
  {                                                                            \
    f32x2 p;                                                                   \
    p[0] = __uint_as_float((U).x << 16);                                       \
    p[1] = __uint_as_float((U).x & 0xffff0000u); acc2[0] += p;                 \
    p[0] = __uint_as_float((U).y << 16);                                       \
    p[1] = __uint_as_float((U).y & 0xffff0000u); acc2[1] += p;                 \
    p[0] = __uint_as_float((U).z << 16);                                       \
    p[1] = __uint_as_float((U).z & 0xffff0000u); acc2[2] += p;                 \
    p[0] = __uint_as_float((U).w << 16);                                       \
    p[1] = __uint_as_float((U).w & 0xffff0000u); acc2[3] += p;                 \
  }
#define ACCFMA(U, M)                                                           \
  {                                                                            \
    f32x2 w2; w2[0] = (M); w2[1] = (M);                                        \
    f32x2 p;                                                                   \
    p[0] = __uint_as_float((U).x << 16);                                       \
    p[1] = __uint_as_float((U).x & 0xffff0000u); acc2[0] += p * w2;            \
    p[0] = __uint_as_float((U).y << 16);                                       \
    p[1] = __uint_as_float((U).y & 0xffff0000u); acc2[1] += p * w2;            \
    p[0] = __uint_as_float((U).z << 16);                                       \
    p[1] = __uint_as_float((U).z & 0xffff0000u); acc2[2] += p * w2;            \
    p[0] = __uint_as_float((U).w << 16);                                       \
    p[1] = __uint_as_float((U).w & 0xffff0000u); acc2[3] += p * w2;            \
  }

  for (int base = -1; base < deg; base += 64) {
    int idx = base + lane;
    int s = node;  // slot -1 (self) and invalid slots default to node
    if (idx >= 0 && idx < deg) s = csr[beg + idx];
    int cntv = deg - base; if (cntv > 64) cntv = 64;
    int j = 0;
    for (; j + 8 <= cntv; j += 8) {  // all 8 slots valid: no mask needed
      int s0 = __shfl(s, j + g);
      int s1 = __shfl(s, j + 4 + g);
      uint4 u0 = *(const uint4*)(hs + (size_t)s0 * 128 + r * 8);
      uint4 u1 = *(const uint4*)(hs + (size_t)s1 * 128 + r * 8);
      ACCADD(u0); ACCADD(u1);
    }
    for (; j < cntv; j += 4) {
      int sj = __shfl(s, j + g);
      float mk = (j + g < cntv) ? 1.f : 0.f;  // wave-uniform per group
      uint4 u = *(const uint4*)(hs + (size_t)sj * 128 + r * 8);
      ACCFMA(u, mk);
    }
  }
#undef ACCADD
#undef ACCFMA

  float a[8];
#pragma unroll
  for (int d = 0; d < 4; d++) { a[2 * d] = acc2[d][0]; a[2 * d + 1] = acc2[d][1]; }
#pragma unroll
  for (int i = 0; i < 8; i++) {
    a[i] += __shfl_xor(a[i], 16);
    a[i] += __shfl_xor(a[i], 32);
  }

  if (g == 0) {
    bf16x8 t;
#pragma unroll
    for (int i = 0; i < 8; i++) {
      float v = a[i] * di + bias[r * 8 + i];
      if (v < 0.f) v = 0.f;
      t[i] = (short)f2bf(v);
    }
    *(bf16x8*)(out + (size_t)node * 128 + r * 8) = t;
  }
}

extern "C" void kernel_launch(void* const* d_in, const int* in_sizes, int n_in,
                              void* d_out, int out_size, void* d_ws, size_t ws_size,
                              hipStream_t stream) {
  const float* x  = (const float*)d_in[0];
  const int* ei   = (const int*)d_in[1];
  const float* W1 = (const float*)d_in[2];
  const float* b1 = (const float*)d_in[3];
  const float* W2 = (const float*)d_in[4];
  const float* b2 = (const float*)d_in[5];
  const float* fcW = (const float*)d_in[6];
  const float* fcb = (const float*)d_in[7];
  float* out = (float*)d_out;

  int N = in_sizes[0] / 128;  // 100000
  int E = in_sizes[1] / 2;    // 1600000
  int B = (N + 255) >> 8;     // 391 buckets
  const int* src = ei;
  const int* dst = ei + E;

  char* w = (char*)d_ws;
  auto alloc = [&](size_t b) { char* p = w; w += (b + 255) & ~(size_t)255; return p; };
  float* dinv      = (float*)alloc((size_t)N * 4);
  int*   row_start = (int*)alloc((size_t)(N + 1) * 4);
  int*   batom     = (int*)alloc((size_t)(B + 1) * 128);  // bcnt + bfill, stride-16 each
  int*   bcnt      = batom;
  int*   bfill     = batom + (size_t)(B + 1) * 16;
  unsigned* ebuf   = (unsigned*)alloc((size_t)E * 4);
  int*   csr       = (int*)alloc((size_t)E * 4);
  unsigned short* bufA = (unsigned short*)alloc((size_t)N * 128 * 2);
  unsigned short* bufB = (unsigned short*)alloc((size_t)N * 128 * 2);

  hipMemsetAsync(batom, 0, (size_t)(B + 1) * 128, stream);

  bhist_k<<<256, 256, 0, stream>>>(dst, bcnt, E, B);
  bin_k<<<256, 256, 0, stream>>>(src, dst, bcnt, bfill, ebuf, E, B);
  bsort_k<<<B, 256, 0, stream>>>(ebuf, bcnt, csr, row_start, dinv, N, B, E);

  // layer 1: hs1 = (x @ W1) * dinv[row]   (fp32 in, bf16 out, row-scaled)
  gemm_k<128, true, false, true><<<782, 256, 0, stream>>>((const void*)x, W1, nullptr, dinv,
                                                          (void*)bufA, N);
  // agg1: a1 = relu(sum(hs1) * dinv + b1)  (bf16)
  agg_k<<<(N + 3) / 4, 256, 0, stream>>>(bufA, dinv, row_start, csr, b1, bufB, N);
  // layer 2: hs2 = (a1 @ W2) * dinv[row]
  gemm_k<128, false, false, true><<<782, 256, 0, stream>>>((const void*)bufB, W2, nullptr, dinv,
                                                           (void*)bufA, N);
  // agg2: a2 = relu(sum(hs2) * dinv + b2)
  agg_k<<<(N + 3) / 4, 256, 0, stream>>>(bufA, dinv, row_start, csr, b2, bufB, N);
  // fc: out = a2 @ fcW + fcb  (fp32 out)
  gemm_k<64, false, true, false><<<782, 256, 0, stream>>>((const void*)bufB, fcW, fcb, nullptr,
                                                          (void*)out, N);
}